// Round 5
// baseline (177.993 us; speedup 1.0000x reference)
//
#include <hip/hip_runtime.h>

// filtfilt with a=[1,0] (pure FIR, zero ICs both passes) collapses per row to:
//   y[n]   = (b0^2+b1^2)*x[n] + b0*b1*(x[n-1]+x[n+1])   for 0 <= n < T-1 (x[-1]=0)
//   y[T-1] =  b0^2     *x[T-1] + b0*b1* x[T-2]          (no y1[T] term)
// then clip to [-1,1].
//
// 64 B/thread (four 16B vectors), one chunk per thread (exact grid, no loop).
// Cross-lane neighbors via wave shuffles; T/16 = 65536 is a multiple of 64, so
// row boundaries only land on lanes 0/63. nt-stores keep the input L3-resident
// (measured: FETCH dropped to ~138MB once stores bypassed cache).

typedef float fx4 __attribute__((ext_vector_type(4)));

#define T_LEN 1048576LL          // row length (2^20), from the reference
#define T16 (T_LEN / 16)         // 64B-chunks per row (65536, multiple of 64)

__global__ __launch_bounds__(256) void preem_filtfilt_kernel(
    const float* __restrict__ x,
    const float* __restrict__ b,
    float* __restrict__ out,
    long long n16)
{
    const long long i = (long long)blockIdx.x * blockDim.x + threadIdx.x;
    if (i >= n16) return;

    const float b0 = b[0];
    const float b1 = b[1];
    const float c0 = b0 * b0 + b1 * b1;   // center tap (interior)
    const float c1 = b0 * b1;             // neighbor tap
    const float c0_last = b0 * b0;        // center tap at n = T-1

    const int lane = threadIdx.x & 63;
    const long long base = i * 16;

    const fx4 v0 = *(const fx4*)(x + base);
    const fx4 v1 = *(const fx4*)(x + base + 4);
    const fx4 v2 = *(const fx4*)(x + base + 8);
    const fx4 v3 = *(const fx4*)(x + base + 12);

    // cross-lane neighbors (lane i-1's v3.w, lane i+1's v0.x)
    float prev = __shfl_up(v3.w, 1, 64);
    float next = __shfl_down(v0.x, 1, 64);

    const long long col = i & (T16 - 1);
    const bool first = (col == 0);         // only possible at lane 0
    const bool last  = (col == T16 - 1);   // only possible at lane 63
    if (lane == 0)  prev = first ? 0.0f : x[base - 1];
    if (lane == 63) next = last  ? 0.0f : x[base + 16];
    const float cw = last ? c0_last : c0;

    fx4 o0, o1, o2, o3;
    o0.x = c0 * v0.x + c1 * (prev + v0.y);
    o0.y = c0 * v0.y + c1 * (v0.x + v0.z);
    o0.z = c0 * v0.z + c1 * (v0.y + v0.w);
    o0.w = c0 * v0.w + c1 * (v0.z + v1.x);
    o1.x = c0 * v1.x + c1 * (v0.w + v1.y);
    o1.y = c0 * v1.y + c1 * (v1.x + v1.z);
    o1.z = c0 * v1.z + c1 * (v1.y + v1.w);
    o1.w = c0 * v1.w + c1 * (v1.z + v2.x);
    o2.x = c0 * v2.x + c1 * (v1.w + v2.y);
    o2.y = c0 * v2.y + c1 * (v2.x + v2.z);
    o2.z = c0 * v2.z + c1 * (v2.y + v2.w);
    o2.w = c0 * v2.w + c1 * (v2.z + v3.x);
    o3.x = c0 * v3.x + c1 * (v2.w + v3.y);
    o3.y = c0 * v3.y + c1 * (v3.x + v3.z);
    o3.z = c0 * v3.z + c1 * (v3.y + v3.w);
    o3.w = cw * v3.w + c1 * (v3.z + next);

    o0.x = fminf(fmaxf(o0.x, -1.0f), 1.0f);
    o0.y = fminf(fmaxf(o0.y, -1.0f), 1.0f);
    o0.z = fminf(fmaxf(o0.z, -1.0f), 1.0f);
    o0.w = fminf(fmaxf(o0.w, -1.0f), 1.0f);
    o1.x = fminf(fmaxf(o1.x, -1.0f), 1.0f);
    o1.y = fminf(fmaxf(o1.y, -1.0f), 1.0f);
    o1.z = fminf(fmaxf(o1.z, -1.0f), 1.0f);
    o1.w = fminf(fmaxf(o1.w, -1.0f), 1.0f);
    o2.x = fminf(fmaxf(o2.x, -1.0f), 1.0f);
    o2.y = fminf(fmaxf(o2.y, -1.0f), 1.0f);
    o2.z = fminf(fmaxf(o2.z, -1.0f), 1.0f);
    o2.w = fminf(fmaxf(o2.w, -1.0f), 1.0f);
    o3.x = fminf(fmaxf(o3.x, -1.0f), 1.0f);
    o3.y = fminf(fmaxf(o3.y, -1.0f), 1.0f);
    o3.z = fminf(fmaxf(o3.z, -1.0f), 1.0f);
    o3.w = fminf(fmaxf(o3.w, -1.0f), 1.0f);

    __builtin_nontemporal_store(o0, (fx4*)(out + base));
    __builtin_nontemporal_store(o1, (fx4*)(out + base + 4));
    __builtin_nontemporal_store(o2, (fx4*)(out + base + 8));
    __builtin_nontemporal_store(o3, (fx4*)(out + base + 12));
}

extern "C" void kernel_launch(void* const* d_in, const int* in_sizes, int n_in,
                              void* d_out, int out_size, void* d_ws, size_t ws_size,
                              hipStream_t stream) {
    const float* x = (const float*)d_in[0];
    const float* b = (const float*)d_in[1];
    float* out = (float*)d_out;

    const long long n = (long long)in_sizes[0];   // B*T = 67,108,864
    const long long n16 = n / 16;                 // 4,194,304 64B-chunks

    const int block = 256;
    const int grid = (int)((n16 + block - 1) / block);   // 16384 blocks

    preem_filtfilt_kernel<<<grid, block, 0, stream>>>(x, b, out, n16);
}

// Round 6
// 82.038 us; speedup vs baseline: 2.1696x; 2.1696x over previous
//
#include <hip/hip_runtime.h>

// filtfilt with a=[1,0] (pure FIR, zero ICs both passes) collapses per row to:
//   y[n]   = (b0^2+b1^2)*x[n] + b0*b1*(x[n-1]+x[n+1])   for 0 <= n < T-1 (x[-1]=0)
//   y[T-1] =  b0^2     *x[T-1] + b0*b1* x[T-2]          (no y1[T] term)
// then clip to [-1,1].
//
// 4 float4 chunks per thread, BLOCK-STRIDED so each instruction's wave access
// is 64 lanes x 16B = 1024B contiguous (R5 post-mortem: per-thread-contiguous
// layout caused 1.7x write amplification with nt-stores). Cross-lane neighbors
// via shuffles; wave chunk bases are multiples of 64 and T/4 = 262144 is a
// multiple of 64, so row boundaries only land on lanes 0/63.

typedef float fx4 __attribute__((ext_vector_type(4)));

#define T_LEN 1048576LL          // row length (2^20), from the reference
#define T4 (T_LEN / 4)           // float4s per row (262144, multiple of 64)
#define CHUNKS 4                 // float4s per thread

__global__ __launch_bounds__(256) void preem_filtfilt_kernel(
    const float* __restrict__ x,
    const float* __restrict__ b,
    float* __restrict__ out)
{
    const float b0 = b[0];
    const float b1 = b[1];
    const float c0 = b0 * b0 + b1 * b1;   // center tap (interior)
    const float c1 = b0 * b1;             // neighbor tap
    const float c0_last = b0 * b0;        // center tap at n = T-1

    const int lane = threadIdx.x & 63;
    const long long blockBase = (long long)blockIdx.x * (256 * CHUNKS);

    const fx4* __restrict__ x4 = (const fx4*)x;
    fx4* __restrict__ o4 = (fx4*)out;

    // 4 independent loads issued back-to-back for memory-level parallelism
    long long c[CHUNKS];
    fx4 v[CHUNKS];
#pragma unroll
    for (int k = 0; k < CHUNKS; ++k) {
        c[k] = blockBase + k * 256 + threadIdx.x;
        v[k] = x4[c[k]];
    }

#pragma unroll
    for (int k = 0; k < CHUNKS; ++k) {
        const long long ci = c[k];
        const fx4 vv = v[k];

        // neighbors: lane l-1 owns chunk ci-1 (its .w = x[4ci-1]),
        //            lane l+1 owns chunk ci+1 (its .x = x[4ci+4])
        float prev = __shfl_up(vv.w, 1, 64);
        float next = __shfl_down(vv.x, 1, 64);

        const long long col4 = ci & (T4 - 1);
        const bool first = (col4 == 0);        // only possible at lane 0
        const bool last  = (col4 == T4 - 1);   // only possible at lane 63
        if (lane == 0)  prev = first ? 0.0f : x[ci * 4 - 1];
        if (lane == 63) next = last  ? 0.0f : x[ci * 4 + 4];
        const float cw = last ? c0_last : c0;

        fx4 o;
        o.x = c0 * vv.x + c1 * (prev + vv.y);
        o.y = c0 * vv.y + c1 * (vv.x + vv.z);
        o.z = c0 * vv.z + c1 * (vv.y + vv.w);
        o.w = cw * vv.w + c1 * (vv.z + next);

        o.x = fminf(fmaxf(o.x, -1.0f), 1.0f);
        o.y = fminf(fmaxf(o.y, -1.0f), 1.0f);
        o.z = fminf(fmaxf(o.z, -1.0f), 1.0f);
        o.w = fminf(fmaxf(o.w, -1.0f), 1.0f);

        __builtin_nontemporal_store(o, &o4[ci]);
    }
}

extern "C" void kernel_launch(void* const* d_in, const int* in_sizes, int n_in,
                              void* d_out, int out_size, void* d_ws, size_t ws_size,
                              hipStream_t stream) {
    const float* x = (const float*)d_in[0];
    const float* b = (const float*)d_in[1];
    float* out = (float*)d_out;

    const long long n = (long long)in_sizes[0];   // B*T = 67,108,864
    const long long n4 = n / 4;                   // 16,777,216 float4s
    const int block = 256;
    const int grid = (int)(n4 / (block * CHUNKS));   // exactly 16384 blocks

    preem_filtfilt_kernel<<<grid, block, 0, stream>>>(x, b, out);
}